// Round 8
// baseline (922.511 us; speedup 1.0000x reference)
//
#include <hip/hip_runtime.h>
#include <stdint.h>

#define N_NODES 100000
#define N_EDGES 3200000
#define N_REL   16
#define NBKT    391         // ceil(100000/256) buckets of 256 nodes (bucket = src >> 8)
#define NBLK    128         // partition blocks; 3.2M/128 = 25000 edges each
#define EPB     25000
#define BKT_PAD 1800        // per-bucket pad allowance (multiple of 8), >= 256*7+7
#define PADDED_E (N_EDGES + 8 + NBKT * BKT_PAD)
#define PAD_FLAG 0x80000000u
// EMB=32, N_CLS=50, BATCH=1024

typedef __attribute__((ext_vector_type(8))) short  short8;
typedef __attribute__((ext_vector_type(4))) short  short4_t;
typedef __attribute__((ext_vector_type(4))) float  f32x4;

static __device__ __forceinline__ int align8(int x) { return (x + 7) & ~7; }

static __device__ __forceinline__ unsigned short f32_to_bf16(float f) {
    union { float f; unsigned int u; } v; v.f = f;
    unsigned int u = v.u;
    unsigned int r = u + 0x7FFFu + ((u >> 16) & 1u);   // RNE
    return (unsigned short)(r >> 16);
}
static __device__ __forceinline__ float bf2f(unsigned short s) {
    union { unsigned int u; float f; } cv; cv.u = ((unsigned int)s) << 16;
    return cv.f;
}

// ---------------- emb0 f32 -> bf16 table (6.4 MB gather target) ----------------
__global__ void k_embcast(const float* __restrict__ emb0, unsigned short* __restrict__ embbf) {
    int t = blockIdx.x * 256 + threadIdx.x;          // 3125 x 256
    f32x4 v = ((const f32x4*)emb0)[t];
    short4_t o;
#pragma unroll
    for (int e = 0; e < 4; ++e) o[e] = (short)f32_to_bf16(v[e]);
    ((short4_t*)embbf)[t] = o;
}

// ---------------- WcatT[i][k] = bf16(W1[k>>5][i][k&31]),  32 x 512 ----------------
__global__ void k_wcast(const float* __restrict__ W1, unsigned short* __restrict__ WcatT) {
    for (int t = threadIdx.x; t < 32 * 512; t += 512) {
        int i = t >> 9, k = t & 511;
        WcatT[t] = f32_to_bf16(W1[(size_t)(k >> 5) * 1024 + i * 32 + (k & 31)]);
    }
}

// ---------------- phase A: per-block bucket histogram (LDS atomics only) ----------------
__global__ __launch_bounds__(256) void k_histA(const int* __restrict__ src,
                                               int* __restrict__ table) {
    __shared__ int lh[NBKT];
    int tid = threadIdx.x, bid = blockIdx.x;
    for (int t = tid; t < NBKT; t += 256) lh[t] = 0;
    __syncthreads();
    int e0 = bid * EPB;
    for (int e = e0 + tid; e < e0 + EPB; e += 256)
        atomicAdd(&lh[src[e] >> 8], 1);
    __syncthreads();
    for (int t = tid; t < NBKT; t += 256) table[bid * NBKT + t] = lh[t];
}

// ---------------- bucket totals ----------------
__global__ void k_btot(const int* __restrict__ table, int* __restrict__ btot) {
    int b = blockIdx.x * 256 + threadIdx.x;
    if (b >= NBKT) return;
    int s = 0;
    for (int k = 0; k < NBLK; ++k) s += table[k * NBKT + b];
    btot[b] = s;
}

// ---------------- bucket bases: exclusive scan of btot[391] (raw edge counts) ----------
__global__ void k_bbase(const int* __restrict__ btot, int* __restrict__ bktbase) {
    __shared__ int sd[512];
    int tid = threadIdx.x;
    int v = (tid < NBKT) ? btot[tid] : 0;
    sd[tid] = v; __syncthreads();
    int x = v;
    for (int off = 1; off < 512; off <<= 1) {
        int t = (tid >= off) ? sd[tid - off] : 0;
        __syncthreads();
        x += t; sd[tid] = x;
        __syncthreads();
    }
    if (tid < NBKT) bktbase[tid] = x - v;
    if (tid == 0) bktbase[NBKT] = N_EDGES;
}

// ---------------- per-(bucket,block) offsets in PADDED space: goff[block][bkt] ----------
__global__ void k_goff(const int* __restrict__ table, const int* __restrict__ bktbase,
                       int* __restrict__ goff) {
    __shared__ int sd[NBLK];
    int b = blockIdx.x;           // bucket
    int tid = threadIdx.x;        // block index (128 threads)
    int v = table[tid * NBKT + b];
    sd[tid] = v; __syncthreads();
    int x = v;
    for (int off = 1; off < NBLK; off <<= 1) {
        int t = (tid >= off) ? sd[tid - off] : 0;
        __syncthreads();
        x += t; sd[tid] = x;
        __syncthreads();
    }
    int bp = align8(bktbase[b]) + b * BKT_PAD;    // padded, 8-aligned bucket base
    goff[tid * NBKT + b] = bp + (x - v);
}

// ---------------- phase C: partition into buckets, single-owner write streams ----------
// entry = slow(8) << 21 | rel(4) << 17 | dst(17)
__global__ __launch_bounds__(256) void k_partB(const int* __restrict__ src,
                                               const int* __restrict__ rel,
                                               const int* __restrict__ dst,
                                               const int* __restrict__ goff,
                                               unsigned int* __restrict__ part) {
    __shared__ int lcur[NBKT];
    int tid = threadIdx.x, bid = blockIdx.x;
    for (int t = tid; t < NBKT; t += 256) lcur[t] = goff[bid * NBKT + t];
    __syncthreads();
    int e0 = bid * EPB;
    for (int e = e0 + tid; e < e0 + EPB; e += 256) {
        int s = src[e];
        int pos = atomicAdd(&lcur[s >> 8], 1);
        part[pos] = ((unsigned)(s & 255) << 21) | ((unsigned)rel[e] << 17) | (unsigned)dst[e];
    }
}

// ---------------- k_place: node-exact placement (8-padded) + offs/cnt/inv2 ------------
__global__ __launch_bounds__(256) void k_place(const unsigned int* __restrict__ part,
                                               const int* __restrict__ bktbase,
                                               unsigned int* __restrict__ sorted_rd,
                                               int* __restrict__ sorted_src,
                                               int* __restrict__ offs,
                                               int* __restrict__ cnt,
                                               float* __restrict__ inv2) {
    __shared__ int lhist[256 * 16];    // (node-in-bucket, rel) counts
    __shared__ int sd[256];            // scan temp
    __shared__ int lcur[256];          // node cursors
    int b = blockIdx.x, tid = threadIdx.x;
    int n0 = b << 8;
    int braw = bktbase[b];
    int bsize = bktbase[b + 1] - braw;
    int bp = align8(braw) + b * BKT_PAD;                    // content base (8-aligned)
    int bp_next = align8(bktbase[b + 1]) + (b + 1) * BKT_PAD;
#pragma unroll
    for (int k = 0; k < 16; ++k) lhist[tid + k * 256] = 0;
    __syncthreads();
    // pass 1: (node,rel) histogram over this bucket's content
    for (int t = bp + tid; t < bp + bsize; t += 256)
        atomicAdd(&lhist[part[t] >> 17], 1);   // (slow<<4)|rel, < 4096
    __syncthreads();
    // per-node counts (raw + padded) + exclusive scan of padded counts
    int ncnt = 0;
#pragma unroll
    for (int r = 0; r < 16; ++r) ncnt += lhist[(tid << 4) | r];
    int ncnt_p = align8(ncnt);
    sd[tid] = ncnt_p; __syncthreads();
    int x = ncnt_p;
    for (int off = 1; off < 256; off <<= 1) {
        int t = (tid >= off) ? sd[tid - off] : 0;
        __syncthreads();
        x += t; sd[tid] = x;
        __syncthreads();
    }
    int nodeoff = bp + (x - ncnt_p);
    lcur[tid] = nodeoff;
    int node = n0 + tid;
    if (node < N_NODES) { offs[node] = nodeoff; cnt[node] = ncnt; }
    // inv2 emission
    for (int t = tid; t < 4096; t += 256) {
        int nd = n0 + (t >> 4);
        if (nd < N_NODES) {
            int c = lhist[t];
            inv2[((size_t)nd << 4) + (t & 15)] = c ? 1.0f / (float)c : 0.f;
        }
    }
    __syncthreads();
    // pass 2: exact placement of real edges
    for (int t = bp + tid; t < bp + bsize; t += 256) {
        unsigned int v = part[t];
        int j = (int)(v >> 21);
        int p = atomicAdd(&lcur[j], 1);
        sorted_rd[p] = v & 0x1FFFFFu;
        if (b < 4) sorted_src[p] = n0 + j;    // buckets 0..3 = nodes 0..1023
    }
    __syncthreads();
    // pass 3: per-node pad fill (<=7 each) + inter-bucket gap fill
    for (int p = nodeoff + ncnt; p < nodeoff + ncnt_p; ++p) sorted_rd[p] = PAD_FLAG;
    int content_end = bp + sd[255];
    for (int t = content_end + tid; t < bp_next; t += 256) sorted_rd[t] = PAD_FLAG;
}

// ---------------- fused layer-1: aggregate-first + MFMA transform ----------------
// Block = 8 nodes (512 thr, 8 waves; wave w owns node n0+w). Edge segments 8-padded,
// 8-aligned. LDS agg[8][16][32] f32 accumulated via ds_add_f32 (no RMW, no 2nd copy).
// 8 gathers in flight per half-wave via 2x uint4 edge loads. Then inv-scale -> bf16
// aggb, 2 waves apply Wcat via MFMA (M=16,K=512,N=32), relu-fused h1 write.
__global__ __launch_bounds__(512) void k_l1agg(const unsigned int* __restrict__ sorted_rd,
                                               const int* __restrict__ offs,
                                               const int* __restrict__ cnt,
                                               const float* __restrict__ inv2,
                                               const unsigned short* __restrict__ embbf,
                                               const unsigned short* __restrict__ WcatT,
                                               float* __restrict__ h1) {
    __shared__ float agg[8][16][32];         // 16 KB
    __shared__ unsigned short aggb[16][520]; // 16.6 KB
    int tid = threadIdx.x;
    int w = tid >> 6, lane = tid & 63;
    int n0 = blockIdx.x << 3;
    {
        float* a = &agg[0][0][0];
        for (int t = tid; t < 8 * 16 * 32; t += 512) a[t] = 0.f;
        unsigned short* bz = &aggb[8][0];    // rows 8..15 must read as zero in MFMA
        for (int t = tid; t < 8 * 520; t += 512) bz[t] = 0;
    }
    __syncthreads();
    int n = n0 + w;
    int start = offs[n];
    int ecp = align8(cnt[n]);                // padded count, segment 8-aligned
    int h = lane >> 5, i = lane & 31;
    float* myagg = &agg[w][0][0];
    for (int t0 = start + h * 8; t0 < start + ecp; t0 += 16) {
        uint4 qa = *reinterpret_cast<const uint4*>(sorted_rd + t0);
        uint4 qb = *reinterpret_cast<const uint4*>(sorted_rd + t0 + 4);
        unsigned pk[8] = {qa.x, qa.y, qa.z, qa.w, qb.x, qb.y, qb.z, qb.w};
        float v[8];
#pragma unroll
        for (int k = 0; k < 8; ++k) {
            float g = bf2f(embbf[(size_t)(pk[k] & 0x1FFFFu) * 32 + i]); // pad dst=0: hot line
            v[k] = (pk[k] & PAD_FLAG) ? 0.f : g;
        }
#pragma unroll
        for (int k = 0; k < 8; ++k)
            atomicAdd(&myagg[((pk[k] >> 17) & 15) * 32 + i], v[k]);    // ds_add_f32
    }
    // inv-scale + bf16 (wave-local: only own rows, same-wave DS ordering)
#pragma unroll
    for (int q = 0; q < 8; ++q) {
        int k = q * 64 + lane;              // 0..511
        int r = k >> 5, j = k & 31;
        float s = agg[w][r][j] * inv2[((size_t)n << 4) + r];
        aggb[w][k] = f32_to_bf16(s);
    }
    __syncthreads();
    if (w < 2) {   // MFMA: C[16 rows=nodes][32 cols], wave w does cols w*16..+15
        int col16 = lane & 15, kb = lane >> 4;   // kb 0..3
        f32x4 acc = {0.f, 0.f, 0.f, 0.f};
        const unsigned short* wrow = WcatT + (size_t)(w * 16 + col16) * 512;
#pragma unroll
        for (int ks = 0; ks < 16; ++ks) {
            int k0 = ks * 32 + kb * 8;
            short8 a = *(const short8*)&aggb[col16][k0];
            short8 bfr = *(const short8*)&wrow[k0];
            acc = __builtin_amdgcn_mfma_f32_16x16x32_bf16(a, bfr, acc, 0, 0, 0);
        }
#pragma unroll
        for (int reg = 0; reg < 4; ++reg) {
            int row = kb * 4 + reg;              // C row = node-in-block
            if (row < 8)
                h1[(size_t)(n0 + row) * 32 + w * 16 + col16] = fmaxf(acc[reg], 0.f);
        }
    }
}

// ---------------- layer-2 aggregate: agg2[s][r*32+j] += val * h1relu[d][j] ----------------
__global__ void k_agg2(const unsigned int* __restrict__ sorted_rd,
                       const int* __restrict__ sorted_src,
                       const int* __restrict__ bktbase,
                       const float* __restrict__ inv2, const float* __restrict__ h1,
                       float* __restrict__ agg2) {
    int E2 = ((bktbase[4] + 7) & ~7) + 4 * BKT_PAD;   // padded end of buckets 0..3
    long total = (long)E2 * 32;
    long stride = (long)gridDim.x * blockDim.x;
    for (long t = (long)blockIdx.x * blockDim.x + threadIdx.x; t < total; t += stride) {
        int e = (int)(t >> 5), j = (int)(t & 31);
        unsigned int pk = sorted_rd[e];
        if (pk & PAD_FLAG) continue;                   // pad / gap entry
        int r = (int)(pk >> 17), d = (int)(pk & 0x1FFFFu);
        int s = sorted_src[e];
        float val = inv2[((size_t)s << 4) + r];
        atomicAdd(&agg2[(s << 9) + (r << 5) + j], val * h1[d * 32 + j]);
    }
}

// ---------------- layer-2 transform ----------------
__global__ void k_h2(const float* __restrict__ agg2, const float* __restrict__ W2,
                     float* __restrict__ h2pre) {
    int t = blockIdx.x * 256 + threadIdx.x;   // 128 x 256 = 1024*32
    int s = t >> 5, i = t & 31;
    const float* arow = agg2 + (s << 9);
    float acc = 0.f;
#pragma unroll 4
    for (int r = 0; r < 16; ++r) {
        const float* wrow = W2 + r * 1024 + i * 32;
        const float* a = arow + r * 32;
#pragma unroll
        for (int j = 0; j < 32; ++j) acc += wrow[j] * a[j];
    }
    h2pre[t] = acc;
}

// ---------------- classifier ----------------
__global__ void k_cls(const float* __restrict__ h2pre, const float* __restrict__ cls_w,
                      const float* __restrict__ cls_b, float* __restrict__ out) {
    int t = blockIdx.x * 256 + threadIdx.x;
    int b = t >> 6, c = t & 63;
    if (b >= 1024 || c >= 50) return;
    float acc = cls_b[c];
#pragma unroll
    for (int j = 0; j < 32; ++j)
        acc += fmaxf(h2pre[b * 32 + j], 0.f) * cls_w[c * 32 + j];
    out[b * 50 + c] = acc;
}

extern "C" void kernel_launch(void* const* d_in, const int* in_sizes, int n_in,
                              void* d_out, int out_size, void* d_ws, size_t ws_size,
                              hipStream_t stream) {
    const float* emb0  = (const float*)d_in[0];
    const float* W1    = (const float*)d_in[1];
    const float* W2    = (const float*)d_in[2];
    const float* cls_w = (const float*)d_in[3];
    const float* cls_b = (const float*)d_in[4];
    const int*   src   = (const int*)d_in[5];
    const int*   rel   = (const int*)d_in[6];
    const int*   dst   = (const int*)d_in[7];
    float* out = (float*)d_out;

    char* ws = (char*)d_ws;
    size_t off = 0;
    auto alloc = [&](size_t bytes) -> void* {
        void* p = ws + off;
        off = (off + bytes + 255) & ~((size_t)255);
        return p;
    };
    float*          inv2       = (float*)alloc((size_t)N_NODES * 16 * 4);    // 6.4 MB
    int*            offs       = (int*)alloc((size_t)N_NODES * 4);
    int*            cnt        = (int*)alloc((size_t)N_NODES * 4);
    int*            table      = (int*)alloc((size_t)NBLK * NBKT * 4);       // 200 KB
    int*            btot       = (int*)alloc((size_t)NBKT * 4);
    int*            bktbase    = (int*)alloc((size_t)(NBKT + 1) * 4);
    int*            goff       = (int*)alloc((size_t)NBLK * NBKT * 4);       // 200 KB
    unsigned int*   sorted_rd  = (unsigned int*)alloc((size_t)PADDED_E * 4); // 15.6 MB
    int*            sorted_src = (int*)alloc((size_t)PADDED_E * 4);          // 15.6 MB
    unsigned int*   part       = (unsigned int*)alloc((size_t)PADDED_E * 4); // 15.6 MB
    unsigned short* embbf      = (unsigned short*)alloc((size_t)N_NODES * 32 * 2); // 6.4 MB
    unsigned short* WcatT      = (unsigned short*)alloc((size_t)32 * 512 * 2);     // 32 KB
    float*          h1         = (float*)alloc((size_t)N_NODES * 32 * 4);    // 12.8 MB
    float*          agg2       = (float*)alloc((size_t)1024 * 512 * 4);      // 2 MB
    float*          h2pre      = (float*)alloc((size_t)1024 * 32 * 4);

    hipMemsetAsync(agg2, 0, (size_t)1024 * 512 * 4, stream);

    k_embcast<<<3125, 256, 0, stream>>>(emb0, embbf);
    k_wcast  <<<1, 512, 0, stream>>>(W1, WcatT);
    k_histA  <<<NBLK, 256, 0, stream>>>(src, table);
    k_btot   <<<2, 256, 0, stream>>>(table, btot);
    k_bbase  <<<1, 512, 0, stream>>>(btot, bktbase);
    k_goff   <<<NBKT, NBLK, 0, stream>>>(table, bktbase, goff);
    k_partB  <<<NBLK, 256, 0, stream>>>(src, rel, dst, goff, part);
    k_place  <<<NBKT, 256, 0, stream>>>(part, bktbase, sorted_rd, sorted_src, offs, cnt, inv2);
    k_l1agg  <<<12500, 512, 0, stream>>>(sorted_rd, offs, cnt, inv2, embbf, WcatT, h1);
    k_agg2   <<<1024, 256, 0, stream>>>(sorted_rd, sorted_src, bktbase, inv2, h1, agg2);
    k_h2     <<<128, 256, 0, stream>>>(agg2, W2, h2pre);
    k_cls    <<<256, 256, 0, stream>>>(h2pre, cls_w, cls_b, out);
}

// Round 9
// 427.759 us; speedup vs baseline: 2.1566x; 2.1566x over previous
//
#include <hip/hip_runtime.h>
#include <stdint.h>

#define N_NODES 100000
#define N_EDGES 3200000
#define N_REL   16
#define NBKT    391         // ceil(100000/256) buckets of 256 nodes (bucket = src >> 8)
#define NBLK    128         // partition blocks; 3.2M/128 = 25000 edges each
#define EPB     25000
#define BKT_PAD 1800        // per-bucket pad allowance (multiple of 8), >= 256*7+7
#define PADDED_E (N_EDGES + 8 + NBKT * BKT_PAD)
#define PAD_FLAG 0x80000000u
// EMB=32, N_CLS=50, BATCH=1024

typedef __attribute__((ext_vector_type(8))) short  short8;
typedef __attribute__((ext_vector_type(4))) short  short4_t;
typedef __attribute__((ext_vector_type(4))) float  f32x4;

static __device__ __forceinline__ int align8(int x) { return (x + 7) & ~7; }

static __device__ __forceinline__ unsigned short f32_to_bf16(float f) {
    union { float f; unsigned int u; } v; v.f = f;
    unsigned int u = v.u;
    unsigned int r = u + 0x7FFFu + ((u >> 16) & 1u);   // RNE
    return (unsigned short)(r >> 16);
}
static __device__ __forceinline__ float bf2f(unsigned short s) {
    union { unsigned int u; float f; } cv; cv.u = ((unsigned int)s) << 16;
    return cv.f;
}

// ---------------- phase A: per-block bucket histogram (LDS atomics only) ----------------
__global__ __launch_bounds__(256) void k_histA(const int* __restrict__ src,
                                               int* __restrict__ table) {
    __shared__ int lh[NBKT];
    int tid = threadIdx.x, bid = blockIdx.x;
    for (int t = tid; t < NBKT; t += 256) lh[t] = 0;
    __syncthreads();
    int e0 = bid * EPB;
    for (int e = e0 + tid; e < e0 + EPB; e += 256)
        atomicAdd(&lh[src[e] >> 8], 1);
    __syncthreads();
    for (int t = tid; t < NBKT; t += 256) table[bid * NBKT + t] = lh[t];
}

// ---------------- bucket totals ----------------
__global__ void k_btot(const int* __restrict__ table, int* __restrict__ btot) {
    int b = blockIdx.x * 256 + threadIdx.x;
    if (b >= NBKT) return;
    int s = 0;
    for (int k = 0; k < NBLK; ++k) s += table[k * NBKT + b];
    btot[b] = s;
}

// ---------------- bucket bases: exclusive scan of btot[391] (raw edge counts) ----------
__global__ void k_bbase(const int* __restrict__ btot, int* __restrict__ bktbase) {
    __shared__ int sd[512];
    int tid = threadIdx.x;
    int v = (tid < NBKT) ? btot[tid] : 0;
    sd[tid] = v; __syncthreads();
    int x = v;
    for (int off = 1; off < 512; off <<= 1) {
        int t = (tid >= off) ? sd[tid - off] : 0;
        __syncthreads();
        x += t; sd[tid] = x;
        __syncthreads();
    }
    if (tid < NBKT) bktbase[tid] = x - v;
    if (tid == 0) bktbase[NBKT] = N_EDGES;
}

// ---------------- per-(bucket,block) offsets in PADDED space: goff[block][bkt] ----------
__global__ void k_goff(const int* __restrict__ table, const int* __restrict__ bktbase,
                       int* __restrict__ goff) {
    __shared__ int sd[NBLK];
    int b = blockIdx.x;           // bucket
    int tid = threadIdx.x;        // block index (128 threads)
    int v = table[tid * NBKT + b];
    sd[tid] = v; __syncthreads();
    int x = v;
    for (int off = 1; off < NBLK; off <<= 1) {
        int t = (tid >= off) ? sd[tid - off] : 0;
        __syncthreads();
        x += t; sd[tid] = x;
        __syncthreads();
    }
    int bp = align8(bktbase[b]) + b * BKT_PAD;    // padded, 8-aligned bucket base
    goff[tid * NBKT + b] = bp + (x - v);
}

// ---------------- phase C: partition into buckets, single-owner write streams ----------
// entry = slow(8) << 21 | rel(4) << 17 | dst(17)
__global__ __launch_bounds__(256) void k_partB(const int* __restrict__ src,
                                               const int* __restrict__ rel,
                                               const int* __restrict__ dst,
                                               const int* __restrict__ goff,
                                               unsigned int* __restrict__ part) {
    __shared__ int lcur[NBKT];
    int tid = threadIdx.x, bid = blockIdx.x;
    for (int t = tid; t < NBKT; t += 256) lcur[t] = goff[bid * NBKT + t];
    __syncthreads();
    int e0 = bid * EPB;
    for (int e = e0 + tid; e < e0 + EPB; e += 256) {
        int s = src[e];
        int pos = atomicAdd(&lcur[s >> 8], 1);
        part[pos] = ((unsigned)(s & 255) << 21) | ((unsigned)rel[e] << 17) | (unsigned)dst[e];
    }
}

// ---------------- k_place: node-exact placement (8-padded) + offs/cnt/inv2 ------------
__global__ __launch_bounds__(256) void k_place(const unsigned int* __restrict__ part,
                                               const int* __restrict__ bktbase,
                                               unsigned int* __restrict__ sorted_rd,
                                               int* __restrict__ sorted_src,
                                               int* __restrict__ offs,
                                               int* __restrict__ cnt,
                                               float* __restrict__ inv2) {
    __shared__ int lhist[256 * 16];    // (node-in-bucket, rel) counts
    __shared__ int sd[256];            // scan temp
    __shared__ int lcur[256];          // node cursors
    int b = blockIdx.x, tid = threadIdx.x;
    int n0 = b << 8;
    int braw = bktbase[b];
    int bsize = bktbase[b + 1] - braw;
    int bp = align8(braw) + b * BKT_PAD;                    // content base (8-aligned)
    int bp_next = align8(bktbase[b + 1]) + (b + 1) * BKT_PAD;
#pragma unroll
    for (int k = 0; k < 16; ++k) lhist[tid + k * 256] = 0;
    __syncthreads();
    // pass 1: (node,rel) histogram over this bucket's content
    for (int t = bp + tid; t < bp + bsize; t += 256)
        atomicAdd(&lhist[part[t] >> 17], 1);   // (slow<<4)|rel, < 4096
    __syncthreads();
    // per-node counts (raw + padded) + exclusive scan of padded counts
    int ncnt = 0;
#pragma unroll
    for (int r = 0; r < 16; ++r) ncnt += lhist[(tid << 4) | r];
    int ncnt_p = align8(ncnt);
    sd[tid] = ncnt_p; __syncthreads();
    int x = ncnt_p;
    for (int off = 1; off < 256; off <<= 1) {
        int t = (tid >= off) ? sd[tid - off] : 0;
        __syncthreads();
        x += t; sd[tid] = x;
        __syncthreads();
    }
    int nodeoff = bp + (x - ncnt_p);
    lcur[tid] = nodeoff;
    int node = n0 + tid;
    if (node < N_NODES) { offs[node] = nodeoff; cnt[node] = ncnt; }
    // inv2 emission
    for (int t = tid; t < 4096; t += 256) {
        int nd = n0 + (t >> 4);
        if (nd < N_NODES) {
            int c = lhist[t];
            inv2[((size_t)nd << 4) + (t & 15)] = c ? 1.0f / (float)c : 0.f;
        }
    }
    __syncthreads();
    // pass 2: exact placement of real edges
    for (int t = bp + tid; t < bp + bsize; t += 256) {
        unsigned int v = part[t];
        int j = (int)(v >> 21);
        int p = atomicAdd(&lcur[j], 1);
        sorted_rd[p] = v & 0x1FFFFFu;
        if (b < 4) sorted_src[p] = n0 + j;    // buckets 0..3 = nodes 0..1023
    }
    __syncthreads();
    // pass 3: per-node pad fill (<=7 each) + inter-bucket gap fill
    for (int p = nodeoff + ncnt; p < nodeoff + ncnt_p; ++p) sorted_rd[p] = PAD_FLAG;
    int content_end = bp + sd[255];
    for (int t = content_end + tid; t < bp_next; t += 256) sorted_rd[t] = PAD_FLAG;
}

// ---------------- P[node][rc] = (W1[rc>>5] @ emb0[node])_{rc&31}, bf16 ----------------
// Swapped operands: A = Wcat rows (rc), B = emb0 cols (node), K = 32 = emb dim.
// C: row = rc_local = krow*4+reg (4 consecutive rc), col = node -> one packed 8B store.
__global__ __launch_bounds__(256) void k_pgemm(const float* __restrict__ emb0,
                                               const float* __restrict__ W1,
                                               unsigned short* __restrict__ P,
                                               int nwaves) {
    __shared__ unsigned short wlds[512 * 32];   // bf16(W1 flat [rc][j]), 32 KB
    int tid = threadIdx.x;
    for (int t = tid; t < 4096; t += 256) {     // 4096 f32x4 groups = 16384 f32
        f32x4 v = ((const f32x4*)W1)[t];
        short4_t o;
#pragma unroll
        for (int e = 0; e < 4; ++e) o[e] = (short)f32_to_bf16(v[e]);
        ((short4_t*)wlds)[t] = o;
    }
    __syncthreads();

    int gw   = (blockIdx.x * 256 + tid) >> 6;
    int lane = tid & 63;
    int col16 = lane & 15, krow = lane >> 4;

    const int NTILES = N_NODES / 16;   // 6250 exact
    for (int tile = gw; tile < NTILES; tile += nwaves) {
        int n0 = tile * 16;
        // B fragment: col = node n0+col16, k = j = krow*8..+7
        const float* ap = emb0 + (size_t)(n0 + col16) * 32 + krow * 8;
        f32x4 a0 = *(const f32x4*)ap;
        f32x4 a1 = *(const f32x4*)(ap + 4);
        short8 b;
#pragma unroll
        for (int e = 0; e < 4; ++e) { b[e] = (short)f32_to_bf16(a0[e]); b[e + 4] = (short)f32_to_bf16(a1[e]); }
#pragma unroll
        for (int rcb = 0; rcb < 32; ++rcb) {
            // A fragment: row = rc = rcb*16+col16, k = j = krow*8..+7
            short8 a = *(const short8*)&wlds[(size_t)(rcb * 16 + col16) * 32 + krow * 8];
            f32x4 c = {0.f, 0.f, 0.f, 0.f};
            c = __builtin_amdgcn_mfma_f32_16x16x32_bf16(a, b, c, 0, 0, 0);
            short4_t o;
#pragma unroll
            for (int reg = 0; reg < 4; ++reg) o[reg] = (short)f32_to_bf16(c[reg]);
            // C: col=node n0+col16, rows rc = rcb*16 + krow*4 + (0..3) consecutive
            *(short4_t*)(P + (size_t)(n0 + col16) * 512 + rcb * 16 + krow * 4) = o;
        }
    }
}

// ---------------- layer-1 aggregate: wave per node, 16 P-loads in flight ----------------
__global__ __launch_bounds__(256) void k_agg1(const unsigned int* __restrict__ sorted_rd,
                                              const int* __restrict__ offs,
                                              const int* __restrict__ cnt,
                                              const float* __restrict__ inv2,
                                              const unsigned short* __restrict__ P,
                                              float* __restrict__ h1) {
    int node = blockIdx.x * 4 + (threadIdx.x >> 6);   // 25000 x 256 = 100000 waves
    int lane = threadIdx.x & 63;
    int i = lane & 31, h = lane >> 5;
    int start = offs[node];
    int ecp = align8(cnt[node]);                      // segment 8-aligned + padded
    const float* ivn = inv2 + ((size_t)node << 4);    // 16 floats, one hot line
    float acc = 0.f;
    for (int t0 = start + h * 8; t0 < start + ecp; t0 += 16) {
        uint4 qa = *reinterpret_cast<const uint4*>(sorted_rd + t0);
        uint4 qb = *reinterpret_cast<const uint4*>(sorted_rd + t0 + 4);
        unsigned pk[8] = {qa.x, qa.y, qa.z, qa.w, qb.x, qb.y, qb.z, qb.w};
        float v[8], val[8];
#pragma unroll
        for (int k = 0; k < 8; ++k) {
            unsigned d = pk[k] & 0x1FFFFu, r = (pk[k] >> 17) & 15u;
            v[k]   = bf2f(P[(size_t)d * 512 + r * 32 + i]);   // pad: d=0 hot line
            val[k] = (pk[k] & PAD_FLAG) ? 0.f : ivn[r];
        }
#pragma unroll
        for (int k = 0; k < 8; ++k) acc += val[k] * v[k];
    }
    acc += __shfl_xor(acc, 32, 64);
    if (h == 0) h1[(size_t)node * 32 + i] = fmaxf(acc, 0.f);   // relu fused
}

// ---------------- layer-2 aggregate: agg2[s][r*32+j] += val * h1relu[d][j] ----------------
__global__ void k_agg2(const unsigned int* __restrict__ sorted_rd,
                       const int* __restrict__ sorted_src,
                       const int* __restrict__ bktbase,
                       const float* __restrict__ inv2, const float* __restrict__ h1,
                       float* __restrict__ agg2) {
    int E2 = ((bktbase[4] + 7) & ~7) + 4 * BKT_PAD;   // padded end of buckets 0..3
    long total = (long)E2 * 32;
    long stride = (long)gridDim.x * blockDim.x;
    for (long t = (long)blockIdx.x * blockDim.x + threadIdx.x; t < total; t += stride) {
        int e = (int)(t >> 5), j = (int)(t & 31);
        unsigned int pk = sorted_rd[e];
        if (pk & PAD_FLAG) continue;                   // pad / gap entry
        int r = (int)(pk >> 17), d = (int)(pk & 0x1FFFFu);
        int s = sorted_src[e];
        float val = inv2[((size_t)s << 4) + r];
        atomicAdd(&agg2[(s << 9) + (r << 5) + j], val * h1[(size_t)d * 32 + j]);
    }
}

// ---------------- layer-2 transform ----------------
__global__ void k_h2(const float* __restrict__ agg2, const float* __restrict__ W2,
                     float* __restrict__ h2pre) {
    int t = blockIdx.x * 256 + threadIdx.x;   // 128 x 256 = 1024*32
    int s = t >> 5, i = t & 31;
    const float* arow = agg2 + (s << 9);
    float acc = 0.f;
#pragma unroll 4
    for (int r = 0; r < 16; ++r) {
        const float* wrow = W2 + r * 1024 + i * 32;
        const float* a = arow + r * 32;
#pragma unroll
        for (int j = 0; j < 32; ++j) acc += wrow[j] * a[j];
    }
    h2pre[t] = acc;
}

// ---------------- classifier ----------------
__global__ void k_cls(const float* __restrict__ h2pre, const float* __restrict__ cls_w,
                      const float* __restrict__ cls_b, float* __restrict__ out) {
    int t = blockIdx.x * 256 + threadIdx.x;
    int b = t >> 6, c = t & 63;
    if (b >= 1024 || c >= 50) return;
    float acc = cls_b[c];
#pragma unroll
    for (int j = 0; j < 32; ++j)
        acc += fmaxf(h2pre[b * 32 + j], 0.f) * cls_w[c * 32 + j];
    out[b * 50 + c] = acc;
}

extern "C" void kernel_launch(void* const* d_in, const int* in_sizes, int n_in,
                              void* d_out, int out_size, void* d_ws, size_t ws_size,
                              hipStream_t stream) {
    const float* emb0  = (const float*)d_in[0];
    const float* W1    = (const float*)d_in[1];
    const float* W2    = (const float*)d_in[2];
    const float* cls_w = (const float*)d_in[3];
    const float* cls_b = (const float*)d_in[4];
    const int*   src   = (const int*)d_in[5];
    const int*   rel   = (const int*)d_in[6];
    const int*   dst   = (const int*)d_in[7];
    float* out = (float*)d_out;

    char* ws = (char*)d_ws;
    size_t off = 0;
    auto alloc = [&](size_t bytes) -> void* {
        void* p = ws + off;
        off = (off + bytes + 255) & ~((size_t)255);
        return p;
    };
    float*          inv2       = (float*)alloc((size_t)N_NODES * 16 * 4);    // 6.4 MB
    int*            offs       = (int*)alloc((size_t)N_NODES * 4);
    int*            cnt        = (int*)alloc((size_t)N_NODES * 4);
    int*            table      = (int*)alloc((size_t)NBLK * NBKT * 4);       // 200 KB
    int*            btot       = (int*)alloc((size_t)NBKT * 4);
    int*            bktbase    = (int*)alloc((size_t)(NBKT + 1) * 4);
    int*            goff       = (int*)alloc((size_t)NBLK * NBKT * 4);       // 200 KB
    unsigned int*   sorted_rd  = (unsigned int*)alloc((size_t)PADDED_E * 4); // 15.6 MB
    int*            sorted_src = (int*)alloc((size_t)PADDED_E * 4);          // 15.6 MB
    unsigned short* P          = (unsigned short*)alloc((size_t)N_NODES * 512 * 2); // 102.4 MB
    float*          h1         = (float*)alloc((size_t)N_NODES * 32 * 4);    // 12.8 MB
    float*          agg2       = (float*)alloc((size_t)1024 * 512 * 4);      // 2 MB
    float*          h2pre      = (float*)alloc((size_t)1024 * 32 * 4);
    // part aliases P: part is fully consumed by k_place before k_pgemm writes P
    unsigned int*   part       = (unsigned int*)P;

    hipMemsetAsync(agg2, 0, (size_t)1024 * 512 * 4, stream);

    k_histA <<<NBLK, 256, 0, stream>>>(src, table);
    k_btot  <<<2, 256, 0, stream>>>(table, btot);
    k_bbase <<<1, 512, 0, stream>>>(btot, bktbase);
    k_goff  <<<NBKT, NBLK, 0, stream>>>(table, bktbase, goff);
    k_partB <<<NBLK, 256, 0, stream>>>(src, rel, dst, goff, part);
    k_place <<<NBKT, 256, 0, stream>>>(part, bktbase, sorted_rd, sorted_src, offs, cnt, inv2);
    k_pgemm <<<391, 256, 0, stream>>>(emb0, W1, P, 391 * 4);
    k_agg1  <<<25000, 256, 0, stream>>>(sorted_rd, offs, cnt, inv2, P, h1);
    k_agg2  <<<1024, 256, 0, stream>>>(sorted_rd, sorted_src, bktbase, inv2, h1, agg2);
    k_h2    <<<128, 256, 0, stream>>>(agg2, W2, h2pre);
    k_cls   <<<256, 256, 0, stream>>>(h2pre, cls_w, cls_b, out);
}

// Round 12
// 352.730 us; speedup vs baseline: 2.6153x; 1.2127x over previous
//
#include <hip/hip_runtime.h>
#include <stdint.h>

#define N_NODES 100000
#define N_EDGES 3200000
#define N_REL   16
#define NBKT    391         // ceil(100000/256) buckets of 256 nodes (bucket = src >> 8)
#define NBLK    256         // partition blocks; 3.2M/256 = 12500 edges each
#define EPB     12500
#define BKT_PAD 1800        // per-bucket pad allowance (multiple of 8), >= 256*7+7
#define PADDED_E (N_EDGES + 8 + NBKT * BKT_PAD)
#define PAD_FLAG 0x80000000u
// EMB=32, N_CLS=50, BATCH=1024

typedef __attribute__((ext_vector_type(8))) short  short8;
typedef __attribute__((ext_vector_type(4))) short  short4_t;
typedef __attribute__((ext_vector_type(4))) float  f32x4;

static __device__ __forceinline__ int align8(int x) { return (x + 7) & ~7; }

static __device__ __forceinline__ unsigned short f32_to_bf16(float f) {
    union { float f; unsigned int u; } v; v.f = f;
    unsigned int u = v.u;
    unsigned int r = u + 0x7FFFu + ((u >> 16) & 1u);   // RNE
    return (unsigned short)(r >> 16);
}
static __device__ __forceinline__ float bf2f(unsigned short s) {
    union { unsigned int u; float f; } cv; cv.u = ((unsigned int)s) << 16;
    return cv.f;
}

// ---------------- phase A: per-block bucket histogram (LDS atomics only) ----------------
__global__ __launch_bounds__(512) void k_histA(const int* __restrict__ src,
                                               int* __restrict__ table) {
    __shared__ int lh[NBKT];
    int tid = threadIdx.x, bid = blockIdx.x;
    for (int t = tid; t < NBKT; t += 512) lh[t] = 0;
    __syncthreads();
    int e0 = bid * EPB;
    for (int e = e0 + tid; e < e0 + EPB; e += 512)
        atomicAdd(&lh[src[e] >> 8], 1);
    __syncthreads();
    for (int t = tid; t < NBKT; t += 512) table[bid * NBKT + t] = lh[t];
}

// ---------------- bucket totals ----------------
__global__ void k_btot(const int* __restrict__ table, int* __restrict__ btot) {
    int b = blockIdx.x * 256 + threadIdx.x;
    if (b >= NBKT) return;
    int s = 0;
    for (int k = 0; k < NBLK; ++k) s += table[k * NBKT + b];
    btot[b] = s;
}

// ---------------- bucket bases: exclusive scan of btot[391] (raw edge counts) ----------
__global__ void k_bbase(const int* __restrict__ btot, int* __restrict__ bktbase) {
    __shared__ int sd[512];
    int tid = threadIdx.x;
    int v = (tid < NBKT) ? btot[tid] : 0;
    sd[tid] = v; __syncthreads();
    int x = v;
    for (int off = 1; off < 512; off <<= 1) {
        int t = (tid >= off) ? sd[tid - off] : 0;
        __syncthreads();
        x += t; sd[tid] = x;
        __syncthreads();
    }
    if (tid < NBKT) bktbase[tid] = x - v;
    if (tid == 0) bktbase[NBKT] = N_EDGES;
}

// ---------------- per-(bucket,block) offsets in PADDED space: goff[block][bkt] ----------
__global__ void k_goff(const int* __restrict__ table, const int* __restrict__ bktbase,
                       int* __restrict__ goff) {
    __shared__ int sd[NBLK];
    int b = blockIdx.x;           // bucket
    int tid = threadIdx.x;        // block index (NBLK threads)
    int v = table[tid * NBKT + b];
    sd[tid] = v; __syncthreads();
    int x = v;
    for (int off = 1; off < NBLK; off <<= 1) {
        int t = (tid >= off) ? sd[tid - off] : 0;
        __syncthreads();
        x += t; sd[tid] = x;
        __syncthreads();
    }
    int bp = align8(bktbase[b]) + b * BKT_PAD;    // padded, 8-aligned bucket base
    goff[tid * NBKT + b] = bp + (x - v);
}

// ---------------- phase C: partition into buckets, single-owner write streams ----------
// entry = slow(8) << 21 | rel(4) << 17 | dst(17)
__global__ __launch_bounds__(512) void k_partB(const int* __restrict__ src,
                                               const int* __restrict__ rel,
                                               const int* __restrict__ dst,
                                               const int* __restrict__ goff,
                                               unsigned int* __restrict__ part) {
    __shared__ int lcur[NBKT];
    int tid = threadIdx.x, bid = blockIdx.x;
    for (int t = tid; t < NBKT; t += 512) lcur[t] = goff[bid * NBKT + t];
    __syncthreads();
    int e0 = bid * EPB;
    for (int e = e0 + tid; e < e0 + EPB; e += 512) {
        int s = src[e];
        int pos = atomicAdd(&lcur[s >> 8], 1);
        part[pos] = ((unsigned)(s & 255) << 21) | ((unsigned)rel[e] << 17) | (unsigned)dst[e];
    }
}

// ---------------- k_place: node-exact placement (8-padded) + offs/cnt/inv2 ------------
__global__ __launch_bounds__(256) void k_place(const unsigned int* __restrict__ part,
                                               const int* __restrict__ bktbase,
                                               unsigned int* __restrict__ sorted_rd,
                                               int* __restrict__ sorted_src,
                                               int* __restrict__ offs,
                                               int* __restrict__ cnt,
                                               float* __restrict__ inv2) {
    __shared__ int lhist[256 * 16];    // (node-in-bucket, rel) counts
    __shared__ int sd[256];            // scan temp
    __shared__ int lcur[256];          // node cursors
    int b = blockIdx.x, tid = threadIdx.x;
    int n0 = b << 8;
    int braw = bktbase[b];
    int bsize = bktbase[b + 1] - braw;
    int bp = align8(braw) + b * BKT_PAD;                    // content base (8-aligned)
    int bp_next = align8(bktbase[b + 1]) + (b + 1) * BKT_PAD;
#pragma unroll
    for (int k = 0; k < 16; ++k) lhist[tid + k * 256] = 0;
    __syncthreads();
    // pass 1: (node,rel) histogram over this bucket's content
    for (int t = bp + tid; t < bp + bsize; t += 256)
        atomicAdd(&lhist[part[t] >> 17], 1);   // (slow<<4)|rel, < 4096
    __syncthreads();
    // per-node counts (raw + padded) + exclusive scan of padded counts
    int ncnt = 0;
#pragma unroll
    for (int r = 0; r < 16; ++r) ncnt += lhist[(tid << 4) | r];
    int ncnt_p = align8(ncnt);
    sd[tid] = ncnt_p; __syncthreads();
    int x = ncnt_p;
    for (int off = 1; off < 256; off <<= 1) {
        int t = (tid >= off) ? sd[tid - off] : 0;
        __syncthreads();
        x += t; sd[tid] = x;
        __syncthreads();
    }
    int nodeoff = bp + (x - ncnt_p);
    lcur[tid] = nodeoff;
    int node = n0 + tid;
    if (node < N_NODES) { offs[node] = nodeoff; cnt[node] = ncnt; }
    // inv2 emission
    for (int t = tid; t < 4096; t += 256) {
        int nd = n0 + (t >> 4);
        if (nd < N_NODES) {
            int c = lhist[t];
            inv2[((size_t)nd << 4) + (t & 15)] = c ? 1.0f / (float)c : 0.f;
        }
    }
    __syncthreads();
    // pass 2: exact placement of real edges
    for (int t = bp + tid; t < bp + bsize; t += 256) {
        unsigned int v = part[t];
        int j = (int)(v >> 21);
        int p = atomicAdd(&lcur[j], 1);
        sorted_rd[p] = v & 0x1FFFFFu;
        if (b < 4) sorted_src[p] = n0 + j;    // buckets 0..3 = nodes 0..1023
    }
    __syncthreads();
    // pass 3: per-node pad fill (<=7 each) + inter-bucket gap fill
    for (int p = nodeoff + ncnt; p < nodeoff + ncnt_p; ++p) sorted_rd[p] = PAD_FLAG;
    int content_end = bp + sd[255];
    for (int t = content_end + tid; t < bp_next; t += 256) sorted_rd[t] = PAD_FLAG;
}

// ---------------- P[node][rc] = (W1[rc>>5] @ emb0[node])_{rc&31}, bf16 ----------------
// Swapped operands: A = Wcat rows (rc), B = emb0 cols (node), K = 32 = emb dim.
// C: row = rc_local = krow*4+reg (4 consecutive rc), col = node -> one packed 8B store.
__global__ __launch_bounds__(256) void k_pgemm(const float* __restrict__ emb0,
                                               const float* __restrict__ W1,
                                               unsigned short* __restrict__ P,
                                               int nwaves) {
    __shared__ unsigned short wlds[512 * 32];   // bf16(W1 flat [rc][j]), 32 KB
    int tid = threadIdx.x;
    for (int t = tid; t < 4096; t += 256) {     // 4096 f32x4 groups = 16384 f32
        f32x4 v = ((const f32x4*)W1)[t];
        short4_t o;
#pragma unroll
        for (int e = 0; e < 4; ++e) o[e] = (short)f32_to_bf16(v[e]);
        ((short4_t*)wlds)[t] = o;
    }
    __syncthreads();

    int gw   = (blockIdx.x * 256 + tid) >> 6;
    int lane = tid & 63;
    int col16 = lane & 15, krow = lane >> 4;

    const int NTILES = N_NODES / 16;   // 6250 exact
    for (int tile = gw; tile < NTILES; tile += nwaves) {
        int n0 = tile * 16;
        // B fragment: col = node n0+col16, k = j = krow*8..+7
        const float* ap = emb0 + (size_t)(n0 + col16) * 32 + krow * 8;
        f32x4 a0 = *(const f32x4*)ap;
        f32x4 a1 = *(const f32x4*)(ap + 4);
        short8 b;
#pragma unroll
        for (int e = 0; e < 4; ++e) { b[e] = (short)f32_to_bf16(a0[e]); b[e + 4] = (short)f32_to_bf16(a1[e]); }
#pragma unroll
        for (int rcb = 0; rcb < 32; ++rcb) {
            // A fragment: row = rc = rcb*16+col16, k = j = krow*8..+7
            short8 a = *(const short8*)&wlds[(size_t)(rcb * 16 + col16) * 32 + krow * 8];
            f32x4 c = {0.f, 0.f, 0.f, 0.f};
            c = __builtin_amdgcn_mfma_f32_16x16x32_bf16(a, b, c, 0, 0, 0);
            short4_t o;
#pragma unroll
            for (int reg = 0; reg < 4; ++reg) o[reg] = (short)f32_to_bf16(c[reg]);
            // C: col=node n0+col16, rows rc = rcb*16 + krow*4 + (0..3) consecutive
            *(short4_t*)(P + (size_t)(n0 + col16) * 512 + rcb * 16 + krow * 4) = o;
        }
    }
}

// ---------------- layer-1 aggregate: wave per node, 16 P-loads in flight ----------------
__global__ __launch_bounds__(256) void k_agg1(const unsigned int* __restrict__ sorted_rd,
                                              const int* __restrict__ offs,
                                              const int* __restrict__ cnt,
                                              const float* __restrict__ inv2,
                                              const unsigned short* __restrict__ P,
                                              float* __restrict__ h1) {
    int node = blockIdx.x * 4 + (threadIdx.x >> 6);   // 25000 x 256 = 100000 waves
    int lane = threadIdx.x & 63;
    int i = lane & 31, h = lane >> 5;
    int start = offs[node];
    int ecp = align8(cnt[node]);                      // segment 8-aligned + padded
    const float* ivn = inv2 + ((size_t)node << 4);    // 16 floats, one hot line
    float acc = 0.f;
    for (int t0 = start + h * 8; t0 < start + ecp; t0 += 16) {
        uint4 qa = *reinterpret_cast<const uint4*>(sorted_rd + t0);
        uint4 qb = *reinterpret_cast<const uint4*>(sorted_rd + t0 + 4);
        unsigned pk[8] = {qa.x, qa.y, qa.z, qa.w, qb.x, qb.y, qb.z, qb.w};
        float v[8], val[8];
#pragma unroll
        for (int k = 0; k < 8; ++k) {
            unsigned d = pk[k] & 0x1FFFFu, r = (pk[k] >> 17) & 15u;
            v[k]   = bf2f(P[(size_t)d * 512 + r * 32 + i]);   // pad: d=0 hot line
            val[k] = (pk[k] & PAD_FLAG) ? 0.f : ivn[r];
        }
#pragma unroll
        for (int k = 0; k < 8; ++k) acc += val[k] * v[k];
    }
    acc += __shfl_xor(acc, 32, 64);
    if (h == 0) h1[(size_t)node * 32 + i] = fmaxf(acc, 0.f);   // relu fused
}

// ---------------- layer-2 aggregate: agg2[s][r*32+j] += val * h1relu[d][j] ----------------
__global__ void k_agg2(const unsigned int* __restrict__ sorted_rd,
                       const int* __restrict__ sorted_src,
                       const int* __restrict__ bktbase,
                       const float* __restrict__ inv2, const float* __restrict__ h1,
                       float* __restrict__ agg2) {
    int E2 = ((bktbase[4] + 7) & ~7) + 4 * BKT_PAD;   // padded end of buckets 0..3
    long total = (long)E2 * 32;
    long stride = (long)gridDim.x * blockDim.x;
    for (long t = (long)blockIdx.x * blockDim.x + threadIdx.x; t < total; t += stride) {
        int e = (int)(t >> 5), j = (int)(t & 31);
        unsigned int pk = sorted_rd[e];
        if (pk & PAD_FLAG) continue;                   // pad / gap entry
        int r = (int)(pk >> 17), d = (int)(pk & 0x1FFFFu);
        int s = sorted_src[e];
        float val = inv2[((size_t)s << 4) + r];
        atomicAdd(&agg2[(s << 9) + (r << 5) + j], val * h1[(size_t)d * 32 + j]);
    }
}

// ---------------- layer-2 transform ----------------
__global__ void k_h2(const float* __restrict__ agg2, const float* __restrict__ W2,
                     float* __restrict__ h2pre) {
    int t = blockIdx.x * 256 + threadIdx.x;   // 128 x 256 = 1024*32
    int s = t >> 5, i = t & 31;
    const float* arow = agg2 + (s << 9);
    float acc = 0.f;
#pragma unroll 4
    for (int r = 0; r < 16; ++r) {
        const float* wrow = W2 + r * 1024 + i * 32;
        const float* a = arow + r * 32;
#pragma unroll
        for (int j = 0; j < 32; ++j) acc += wrow[j] * a[j];
    }
    h2pre[t] = acc;
}

// ---------------- classifier ----------------
__global__ void k_cls(const float* __restrict__ h2pre, const float* __restrict__ cls_w,
                      const float* __restrict__ cls_b, float* __restrict__ out) {
    int t = blockIdx.x * 256 + threadIdx.x;
    int b = t >> 6, c = t & 63;
    if (b >= 1024 || c >= 50) return;
    float acc = cls_b[c];
#pragma unroll
    for (int j = 0; j < 32; ++j)
        acc += fmaxf(h2pre[b * 32 + j], 0.f) * cls_w[c * 32 + j];
    out[b * 50 + c] = acc;
}

extern "C" void kernel_launch(void* const* d_in, const int* in_sizes, int n_in,
                              void* d_out, int out_size, void* d_ws, size_t ws_size,
                              hipStream_t stream) {
    const float* emb0  = (const float*)d_in[0];
    const float* W1    = (const float*)d_in[1];
    const float* W2    = (const float*)d_in[2];
    const float* cls_w = (const float*)d_in[3];
    const float* cls_b = (const float*)d_in[4];
    const int*   src   = (const int*)d_in[5];
    const int*   rel   = (const int*)d_in[6];
    const int*   dst   = (const int*)d_in[7];
    float* out = (float*)d_out;

    char* ws = (char*)d_ws;
    size_t off = 0;
    auto alloc = [&](size_t bytes) -> void* {
        void* p = ws + off;
        off = (off + bytes + 255) & ~((size_t)255);
        return p;
    };
    float*          inv2       = (float*)alloc((size_t)N_NODES * 16 * 4);    // 6.4 MB
    int*            offs       = (int*)alloc((size_t)N_NODES * 4);
    int*            cnt        = (int*)alloc((size_t)N_NODES * 4);
    int*            table      = (int*)alloc((size_t)NBLK * NBKT * 4);       // 400 KB
    int*            btot       = (int*)alloc((size_t)NBKT * 4);
    int*            bktbase    = (int*)alloc((size_t)(NBKT + 1) * 4);
    int*            goff       = (int*)alloc((size_t)NBLK * NBKT * 4);       // 400 KB
    unsigned int*   sorted_rd  = (unsigned int*)alloc((size_t)PADDED_E * 4); // 15.6 MB
    int*            sorted_src = (int*)alloc((size_t)PADDED_E * 4);          // 15.6 MB
    unsigned short* P          = (unsigned short*)alloc((size_t)N_NODES * 512 * 2); // 102.4 MB
    float*          h1         = (float*)alloc((size_t)N_NODES * 32 * 4);    // 12.8 MB
    float*          agg2       = (float*)alloc((size_t)1024 * 512 * 4);      // 2 MB
    float*          h2pre      = (float*)alloc((size_t)1024 * 32 * 4);
    // part aliases P: part is fully consumed by k_place before k_pgemm writes P
    unsigned int*   part       = (unsigned int*)P;

    hipMemsetAsync(agg2, 0, (size_t)1024 * 512 * 4, stream);

    k_histA <<<NBLK, 512, 0, stream>>>(src, table);
    k_btot  <<<2, 256, 0, stream>>>(table, btot);
    k_bbase <<<1, 512, 0, stream>>>(btot, bktbase);
    k_goff  <<<NBKT, NBLK, 0, stream>>>(table, bktbase, goff);
    k_partB <<<NBLK, 512, 0, stream>>>(src, rel, dst, goff, part);
    k_place <<<NBKT, 256, 0, stream>>>(part, bktbase, sorted_rd, sorted_src, offs, cnt, inv2);
    k_pgemm <<<391, 256, 0, stream>>>(emb0, W1, P, 391 * 4);
    k_agg1  <<<25000, 256, 0, stream>>>(sorted_rd, offs, cnt, inv2, P, h1);
    k_agg2  <<<1024, 256, 0, stream>>>(sorted_rd, sorted_src, bktbase, inv2, h1, agg2);
    k_h2    <<<128, 256, 0, stream>>>(agg2, W2, h2pre);
    k_cls   <<<256, 256, 0, stream>>>(h2pre, cls_w, cls_b, out);
}

// Round 13
// 345.623 us; speedup vs baseline: 2.6691x; 1.0206x over previous
//
#include <hip/hip_runtime.h>
#include <stdint.h>

#define N_NODES 100000
#define N_EDGES 3200000
#define N_REL   16
#define NBKT    391         // ceil(100000/256) buckets of 256 nodes (bucket = src >> 8)
#define NBLK    256         // partition blocks; 3.2M/256 = 12500 edges each
#define EPB     12500
#define NPGB    200         // pgemm blocks fused after the NBLK partition blocks
#define BKT_PAD 3856        // per-bucket pad allowance (multiple of 16), >= 256*15+15
#define PADDED_E (N_EDGES + 16 + NBKT * BKT_PAD)
#define PAD_FLAG 0x80000000u
// EMB=32, N_CLS=50, BATCH=1024

typedef __attribute__((ext_vector_type(8))) short  short8;
typedef __attribute__((ext_vector_type(4))) short  short4_t;
typedef __attribute__((ext_vector_type(4))) float  f32x4;

static __device__ __forceinline__ int align16i(int x) { return (x + 15) & ~15; }

static __device__ __forceinline__ unsigned short f32_to_bf16(float f) {
    union { float f; unsigned int u; } v; v.f = f;
    unsigned int u = v.u;
    unsigned int r = u + 0x7FFFu + ((u >> 16) & 1u);   // RNE
    return (unsigned short)(r >> 16);
}
static __device__ __forceinline__ float bf2f(unsigned short s) {
    union { unsigned int u; float f; } cv; cv.u = ((unsigned int)s) << 16;
    return cv.f;
}

// ---------------- phase A: per-block bucket histogram (LDS atomics only) ----------------
__global__ __launch_bounds__(512) void k_histA(const int* __restrict__ src,
                                               int* __restrict__ table) {
    __shared__ int lh[NBKT];
    int tid = threadIdx.x, bid = blockIdx.x;
    for (int t = tid; t < NBKT; t += 512) lh[t] = 0;
    __syncthreads();
    int e0 = bid * EPB;
    for (int e = e0 + tid; e < e0 + EPB; e += 512)
        atomicAdd(&lh[src[e] >> 8], 1);
    __syncthreads();
    for (int t = tid; t < NBKT; t += 512) table[bid * NBKT + t] = lh[t];
}

// ---------------- bucket totals ----------------
__global__ void k_btot(const int* __restrict__ table, int* __restrict__ btot) {
    int b = blockIdx.x * 256 + threadIdx.x;
    if (b >= NBKT) return;
    int s = 0;
    for (int k = 0; k < NBLK; ++k) s += table[k * NBKT + b];
    btot[b] = s;
}

// ---------------- bucket bases: exclusive scan of btot[391] (raw edge counts) ----------
__global__ void k_bbase(const int* __restrict__ btot, int* __restrict__ bktbase) {
    __shared__ int sd[512];
    int tid = threadIdx.x;
    int v = (tid < NBKT) ? btot[tid] : 0;
    sd[tid] = v; __syncthreads();
    int x = v;
    for (int off = 1; off < 512; off <<= 1) {
        int t = (tid >= off) ? sd[tid - off] : 0;
        __syncthreads();
        x += t; sd[tid] = x;
        __syncthreads();
    }
    if (tid < NBKT) bktbase[tid] = x - v;
    if (tid == 0) bktbase[NBKT] = N_EDGES;
}

// ---------------- per-(bucket,block) offsets in PADDED space: goff[block][bkt] ----------
__global__ void k_goff(const int* __restrict__ table, const int* __restrict__ bktbase,
                       int* __restrict__ goff) {
    __shared__ int sd[NBLK];
    int b = blockIdx.x;           // bucket
    int tid = threadIdx.x;        // block index (NBLK threads)
    int v = table[tid * NBKT + b];
    sd[tid] = v; __syncthreads();
    int x = v;
    for (int off = 1; off < NBLK; off <<= 1) {
        int t = (tid >= off) ? sd[tid - off] : 0;
        __syncthreads();
        x += t; sd[tid] = x;
        __syncthreads();
    }
    int bp = align16i(bktbase[b]) + b * BKT_PAD;    // padded, 16-aligned bucket base
    goff[tid * NBKT + b] = bp + (x - v);
}

// ---------------- fused: partition (blocks < NBLK) + P-GEMM (blocks >= NBLK) ----------
// Independent work overlapped in one dispatch: partB is latency-bound scatter, pgemm is
// MFMA + streaming 102 MB write. part no longer aliases P (part shares with h1 instead).
__global__ __launch_bounds__(512) void k_partB_pgemm(const int* __restrict__ src,
                                                     const int* __restrict__ rel,
                                                     const int* __restrict__ dst,
                                                     const int* __restrict__ goff,
                                                     unsigned int* __restrict__ part,
                                                     const float* __restrict__ emb0,
                                                     const float* __restrict__ W1,
                                                     unsigned short* __restrict__ P) {
    __shared__ int lcur[NBKT];
    __shared__ unsigned short wlds[512 * 32];   // 32 KB, pgemm path only
    int tid = threadIdx.x, bid = blockIdx.x;
    if (bid < NBLK) {
        // ---- partition: entry = slow(8)<<21 | rel(4)<<17 | dst(17) ----
        for (int t = tid; t < NBKT; t += 512) lcur[t] = goff[bid * NBKT + t];
        __syncthreads();
        int e0 = bid * EPB;
        for (int e = e0 + tid; e < e0 + EPB; e += 512) {
            int s = src[e];
            int pos = atomicAdd(&lcur[s >> 8], 1);
            part[pos] = ((unsigned)(s & 255) << 21) | ((unsigned)rel[e] << 17) | (unsigned)dst[e];
        }
    } else {
        // ---- P[node][rc] = (W1[rc>>5] @ emb0[node])_{rc&31}, bf16 ----
        // A = Wcat rows (rc) from LDS, B = emb0 cols (node), K = 32.
        int pb = bid - NBLK;
        for (int t = tid; t < 4096; t += 512) {     // 16384 f32 of W1 -> bf16 LDS
            f32x4 v = ((const f32x4*)W1)[t];
            short4_t o;
#pragma unroll
            for (int e = 0; e < 4; ++e) o[e] = (short)f32_to_bf16(v[e]);
            ((short4_t*)wlds)[t] = o;
        }
        __syncthreads();
        int gw   = pb * 8 + (tid >> 6);
        int lane = tid & 63;
        int col16 = lane & 15, krow = lane >> 4;
        const int NTILES = N_NODES / 16;   // 6250 exact
        for (int tile = gw; tile < NTILES; tile += NPGB * 8) {
            int n0 = tile * 16;
            const float* ap = emb0 + (size_t)(n0 + col16) * 32 + krow * 8;
            f32x4 a0 = *(const f32x4*)ap;
            f32x4 a1 = *(const f32x4*)(ap + 4);
            short8 b;
#pragma unroll
            for (int e = 0; e < 4; ++e) { b[e] = (short)f32_to_bf16(a0[e]); b[e + 4] = (short)f32_to_bf16(a1[e]); }
#pragma unroll
            for (int rcb = 0; rcb < 32; ++rcb) {
                short8 a = *(const short8*)&wlds[(size_t)(rcb * 16 + col16) * 32 + krow * 8];
                f32x4 c = {0.f, 0.f, 0.f, 0.f};
                c = __builtin_amdgcn_mfma_f32_16x16x32_bf16(a, b, c, 0, 0, 0);
                short4_t o;
#pragma unroll
                for (int reg = 0; reg < 4; ++reg) o[reg] = (short)f32_to_bf16(c[reg]);
                *(short4_t*)(P + (size_t)(n0 + col16) * 512 + rcb * 16 + krow * 4) = o;
            }
        }
    }
}

// ---------------- k_place: node-exact placement (16-padded) + offs/cnt/inv2 ------------
__global__ __launch_bounds__(256) void k_place(const unsigned int* __restrict__ part,
                                               const int* __restrict__ bktbase,
                                               unsigned int* __restrict__ sorted_rd,
                                               int* __restrict__ sorted_src,
                                               int* __restrict__ offs,
                                               int* __restrict__ cnt,
                                               float* __restrict__ inv2) {
    __shared__ int lhist[256 * 16];    // (node-in-bucket, rel) counts
    __shared__ int sd[256];            // scan temp
    __shared__ int lcur[256];          // node cursors
    int b = blockIdx.x, tid = threadIdx.x;
    int n0 = b << 8;
    int braw = bktbase[b];
    int bsize = bktbase[b + 1] - braw;
    int bp = align16i(braw) + b * BKT_PAD;                    // content base (16-aligned)
    int bp_next = align16i(bktbase[b + 1]) + (b + 1) * BKT_PAD;
#pragma unroll
    for (int k = 0; k < 16; ++k) lhist[tid + k * 256] = 0;
    __syncthreads();
    // pass 1: (node,rel) histogram over this bucket's content
    for (int t = bp + tid; t < bp + bsize; t += 256)
        atomicAdd(&lhist[part[t] >> 17], 1);   // (slow<<4)|rel, < 4096
    __syncthreads();
    // per-node counts (raw + padded) + exclusive scan of padded counts
    int ncnt = 0;
#pragma unroll
    for (int r = 0; r < 16; ++r) ncnt += lhist[(tid << 4) | r];
    int ncnt_p = align16i(ncnt);
    sd[tid] = ncnt_p; __syncthreads();
    int x = ncnt_p;
    for (int off = 1; off < 256; off <<= 1) {
        int t = (tid >= off) ? sd[tid - off] : 0;
        __syncthreads();
        x += t; sd[tid] = x;
        __syncthreads();
    }
    int nodeoff = bp + (x - ncnt_p);
    lcur[tid] = nodeoff;
    int node = n0 + tid;
    if (node < N_NODES) { offs[node] = nodeoff; cnt[node] = ncnt; }
    // inv2 emission
    for (int t = tid; t < 4096; t += 256) {
        int nd = n0 + (t >> 4);
        if (nd < N_NODES) {
            int c = lhist[t];
            inv2[((size_t)nd << 4) + (t & 15)] = c ? 1.0f / (float)c : 0.f;
        }
    }
    __syncthreads();
    // pass 2: exact placement of real edges
    for (int t = bp + tid; t < bp + bsize; t += 256) {
        unsigned int v = part[t];
        int j = (int)(v >> 21);
        int p = atomicAdd(&lcur[j], 1);
        sorted_rd[p] = v & 0x1FFFFFu;
        if (b < 4) sorted_src[p] = n0 + j;    // buckets 0..3 = nodes 0..1023
    }
    __syncthreads();
    // pass 3: per-node pad fill (<=15 each) + inter-bucket gap fill
    for (int p = nodeoff + ncnt; p < nodeoff + ncnt_p; ++p) sorted_rd[p] = PAD_FLAG;
    int content_end = bp + sd[255];
    for (int t = content_end + tid; t < bp_next; t += 256) sorted_rd[t] = PAD_FLAG;
}

// ---------------- layer-1 aggregate: wave per node, 32 P-loads in flight ----------------
__global__ __launch_bounds__(256) void k_agg1(const unsigned int* __restrict__ sorted_rd,
                                              const int* __restrict__ offs,
                                              const int* __restrict__ cnt,
                                              const float* __restrict__ inv2,
                                              const unsigned short* __restrict__ P,
                                              float* __restrict__ h1) {
    int node = blockIdx.x * 4 + (threadIdx.x >> 6);   // 25000 x 256 = 100000 waves
    int lane = threadIdx.x & 63;
    int i = lane & 31, h = lane >> 5;
    int start = offs[node];
    int ecp = align16i(cnt[node]);                    // segment 16-aligned + padded
    const float* ivn = inv2 + ((size_t)node << 4);    // 16 floats, one hot line
    float acc = 0.f;
    for (int t0 = start + h * 16; t0 < start + ecp; t0 += 32) {
        uint4 qa = *reinterpret_cast<const uint4*>(sorted_rd + t0);
        uint4 qb = *reinterpret_cast<const uint4*>(sorted_rd + t0 + 4);
        uint4 qc = *reinterpret_cast<const uint4*>(sorted_rd + t0 + 8);
        uint4 qd = *reinterpret_cast<const uint4*>(sorted_rd + t0 + 12);
        unsigned pk[16] = {qa.x, qa.y, qa.z, qa.w, qb.x, qb.y, qb.z, qb.w,
                           qc.x, qc.y, qc.z, qc.w, qd.x, qd.y, qd.z, qd.w};
        float v[16], val[16];
#pragma unroll
        for (int k = 0; k < 16; ++k) {
            unsigned d = pk[k] & 0x1FFFFu, r = (pk[k] >> 17) & 15u;
            v[k]   = bf2f(P[(size_t)d * 512 + r * 32 + i]);   // pad: d=0 hot line
            val[k] = (pk[k] & PAD_FLAG) ? 0.f : ivn[r];
        }
#pragma unroll
        for (int k = 0; k < 16; ++k) acc += val[k] * v[k];
    }
    acc += __shfl_xor(acc, 32, 64);
    if (h == 0) h1[(size_t)node * 32 + i] = fmaxf(acc, 0.f);   // relu fused
}

// ---------------- layer-2 aggregate: agg2[s][r*32+j] += val * h1relu[d][j] ----------------
__global__ void k_agg2(const unsigned int* __restrict__ sorted_rd,
                       const int* __restrict__ sorted_src,
                       const int* __restrict__ bktbase,
                       const float* __restrict__ inv2, const float* __restrict__ h1,
                       float* __restrict__ agg2) {
    int E2 = ((bktbase[4] + 15) & ~15) + 4 * BKT_PAD;   // padded end of buckets 0..3
    long total = (long)E2 * 32;
    long stride = (long)gridDim.x * blockDim.x;
    for (long t = (long)blockIdx.x * blockDim.x + threadIdx.x; t < total; t += stride) {
        int e = (int)(t >> 5), j = (int)(t & 31);
        unsigned int pk = sorted_rd[e];
        if (pk & PAD_FLAG) continue;                   // pad / gap entry
        int r = (int)(pk >> 17), d = (int)(pk & 0x1FFFFu);
        int s = sorted_src[e];
        float val = inv2[((size_t)s << 4) + r];
        atomicAdd(&agg2[(s << 9) + (r << 5) + j], val * h1[(size_t)d * 32 + j]);
    }
}

// ---------------- layer-2 transform ----------------
__global__ void k_h2(const float* __restrict__ agg2, const float* __restrict__ W2,
                     float* __restrict__ h2pre) {
    int t = blockIdx.x * 256 + threadIdx.x;   // 128 x 256 = 1024*32
    int s = t >> 5, i = t & 31;
    const float* arow = agg2 + (s << 9);
    float acc = 0.f;
#pragma unroll 4
    for (int r = 0; r < 16; ++r) {
        const float* wrow = W2 + r * 1024 + i * 32;
        const float* a = arow + r * 32;
#pragma unroll
        for (int j = 0; j < 32; ++j) acc += wrow[j] * a[j];
    }
    h2pre[t] = acc;
}

// ---------------- classifier ----------------
__global__ void k_cls(const float* __restrict__ h2pre, const float* __restrict__ cls_w,
                      const float* __restrict__ cls_b, float* __restrict__ out) {
    int t = blockIdx.x * 256 + threadIdx.x;
    int b = t >> 6, c = t & 63;
    if (b >= 1024 || c >= 50) return;
    float acc = cls_b[c];
#pragma unroll
    for (int j = 0; j < 32; ++j)
        acc += fmaxf(h2pre[b * 32 + j], 0.f) * cls_w[c * 32 + j];
    out[b * 50 + c] = acc;
}

extern "C" void kernel_launch(void* const* d_in, const int* in_sizes, int n_in,
                              void* d_out, int out_size, void* d_ws, size_t ws_size,
                              hipStream_t stream) {
    const float* emb0  = (const float*)d_in[0];
    const float* W1    = (const float*)d_in[1];
    const float* W2    = (const float*)d_in[2];
    const float* cls_w = (const float*)d_in[3];
    const float* cls_b = (const float*)d_in[4];
    const int*   src   = (const int*)d_in[5];
    const int*   rel   = (const int*)d_in[6];
    const int*   dst   = (const int*)d_in[7];
    float* out = (float*)d_out;

    char* ws = (char*)d_ws;
    size_t off = 0;
    auto alloc = [&](size_t bytes) -> void* {
        void* p = ws + off;
        off = (off + bytes + 255) & ~((size_t)255);
        return p;
    };
    float*          inv2       = (float*)alloc((size_t)N_NODES * 16 * 4);    // 6.4 MB
    int*            offs       = (int*)alloc((size_t)N_NODES * 4);
    int*            cnt        = (int*)alloc((size_t)N_NODES * 4);
    int*            table      = (int*)alloc((size_t)NBLK * NBKT * 4);       // 400 KB
    int*            btot       = (int*)alloc((size_t)NBKT * 4);
    int*            bktbase    = (int*)alloc((size_t)(NBKT + 1) * 4);
    int*            goff       = (int*)alloc((size_t)NBLK * NBKT * 4);       // 400 KB
    unsigned int*   sorted_rd  = (unsigned int*)alloc((size_t)PADDED_E * 4); // 18.8 MB
    int*            sorted_src = (int*)alloc((size_t)65536 * 4);             // 256 KB (buckets 0..3 only)
    // part and h1 share one buffer: part dies at k_place, h1 is born at k_agg1
    unsigned int*   partX      = (unsigned int*)alloc((size_t)PADDED_E * 4); // 18.8 MB
    unsigned short* P          = (unsigned short*)alloc((size_t)N_NODES * 512 * 2); // 102.4 MB
    float*          agg2       = (float*)alloc((size_t)1024 * 512 * 4);      // 2 MB
    float*          h2pre      = (float*)alloc((size_t)1024 * 32 * 4);
    unsigned int*   part       = partX;
    float*          h1         = (float*)partX;

    hipMemsetAsync(agg2, 0, (size_t)1024 * 512 * 4, stream);

    k_histA       <<<NBLK, 512, 0, stream>>>(src, table);
    k_btot        <<<2, 256, 0, stream>>>(table, btot);
    k_bbase       <<<1, 512, 0, stream>>>(btot, bktbase);
    k_goff        <<<NBKT, NBLK, 0, stream>>>(table, bktbase, goff);
    k_partB_pgemm <<<NBLK + NPGB, 512, 0, stream>>>(src, rel, dst, goff, part, emb0, W1, P);
    k_place       <<<NBKT, 256, 0, stream>>>(part, bktbase, sorted_rd, sorted_src, offs, cnt, inv2);
    k_agg1        <<<25000, 256, 0, stream>>>(sorted_rd, offs, cnt, inv2, P, h1);
    k_agg2        <<<1024, 256, 0, stream>>>(sorted_rd, sorted_src, bktbase, inv2, h1, agg2);
    k_h2          <<<128, 256, 0, stream>>>(agg2, W2, h2pre);
    k_cls         <<<256, 256, 0, stream>>>(h2pre, cls_w, cls_b, out);
}

// Round 14
// 336.547 us; speedup vs baseline: 2.7411x; 1.0270x over previous
//
#include <hip/hip_runtime.h>
#include <stdint.h>

#define N_NODES 100000
#define N_EDGES 3200000
#define N_REL   16
#define NBKT    391         // ceil(100000/256) buckets of 256 nodes (bucket = src >> 8)
#define NBLK    256         // partition blocks; 3.2M/256 = 12500 edges each
#define EPB     12500
#define BKT_PAD 3856        // per-bucket pad allowance (multiple of 16), >= 256*15+15
#define PADDED_E (N_EDGES + 16 + NBKT * BKT_PAD)
#define PAD_FLAG 0x80000000u
// EMB=32, N_CLS=50, BATCH=1024

typedef __attribute__((ext_vector_type(8))) short  short8;
typedef __attribute__((ext_vector_type(4))) short  short4_t;
typedef __attribute__((ext_vector_type(4))) float  f32x4;

static __device__ __forceinline__ int align16i(int x) { return (x + 15) & ~15; }

static __device__ __forceinline__ unsigned short f32_to_bf16(float f) {
    union { float f; unsigned int u; } v; v.f = f;
    unsigned int u = v.u;
    unsigned int r = u + 0x7FFFu + ((u >> 16) & 1u);   // RNE
    return (unsigned short)(r >> 16);
}
static __device__ __forceinline__ float bf2f(unsigned short s) {
    union { unsigned int u; float f; } cv; cv.u = ((unsigned int)s) << 16;
    return cv.f;
}

// ---------------- phase A: per-block bucket histogram (LDS atomics only) ----------------
__global__ __launch_bounds__(512) void k_histA(const int* __restrict__ src,
                                               int* __restrict__ table) {
    __shared__ int lh[NBKT];
    int tid = threadIdx.x, bid = blockIdx.x;
    for (int t = tid; t < NBKT; t += 512) lh[t] = 0;
    __syncthreads();
    int e0 = bid * EPB;
    for (int e = e0 + tid; e < e0 + EPB; e += 512)
        atomicAdd(&lh[src[e] >> 8], 1);
    __syncthreads();
    for (int t = tid; t < NBKT; t += 512) table[bid * NBKT + t] = lh[t];
}

// ---------------- fused bucket totals + exclusive scan (one block) ----------------
__global__ __launch_bounds__(512) void k_bb(const int* __restrict__ table,
                                            int* __restrict__ bktbase) {
    __shared__ int sd[512];
    int tid = threadIdx.x;
    int v = 0;
    if (tid < NBKT) {
#pragma unroll 8
        for (int k = 0; k < NBLK; ++k) v += table[k * NBKT + tid];
    }
    sd[tid] = v; __syncthreads();
    int x = v;
    for (int off = 1; off < 512; off <<= 1) {
        int t = (tid >= off) ? sd[tid - off] : 0;
        __syncthreads();
        x += t; sd[tid] = x;
        __syncthreads();
    }
    if (tid < NBKT) bktbase[tid] = x - v;
    if (tid == 0) bktbase[NBKT] = N_EDGES;
}

// ---------------- per-(bucket,block) offsets in PADDED space: goff[block][bkt] ----------
__global__ void k_goff(const int* __restrict__ table, const int* __restrict__ bktbase,
                       int* __restrict__ goff) {
    __shared__ int sd[NBLK];
    int b = blockIdx.x;           // bucket
    int tid = threadIdx.x;        // block index (NBLK threads)
    int v = table[tid * NBKT + b];
    sd[tid] = v; __syncthreads();
    int x = v;
    for (int off = 1; off < NBLK; off <<= 1) {
        int t = (tid >= off) ? sd[tid - off] : 0;
        __syncthreads();
        x += t; sd[tid] = x;
        __syncthreads();
    }
    int bp = align16i(bktbase[b]) + b * BKT_PAD;    // padded, 16-aligned bucket base
    goff[tid * NBKT + b] = bp + (x - v);
}

// ---------------- phase C: partition into buckets, single-owner write streams ----------
// entry = slow(8) << 21 | rel(4) << 17 | dst(17)
__global__ __launch_bounds__(512) void k_partB(const int* __restrict__ src,
                                               const int* __restrict__ rel,
                                               const int* __restrict__ dst,
                                               const int* __restrict__ goff,
                                               unsigned int* __restrict__ part) {
    __shared__ int lcur[NBKT];
    int tid = threadIdx.x, bid = blockIdx.x;
    for (int t = tid; t < NBKT; t += 512) lcur[t] = goff[bid * NBKT + t];
    __syncthreads();
    int e0 = bid * EPB;
    for (int e = e0 + tid; e < e0 + EPB; e += 512) {
        int s = src[e];
        int pos = atomicAdd(&lcur[s >> 8], 1);
        part[pos] = ((unsigned)(s & 255) << 21) | ((unsigned)rel[e] << 17) | (unsigned)dst[e];
    }
}

// ---------------- P[node][rc] = (W1[rc>>5] @ emb0[node])_{rc&31}, bf16 ----------------
// A = Wcat rows (rc) from LDS (rows padded to 40 shorts: 2-way banks, 16B-aligned),
// B = emb0 cols (node), K = 32. C col = node -> one packed 8B store per MFMA.
__global__ __launch_bounds__(256) void k_pgemm(const float* __restrict__ emb0,
                                               const float* __restrict__ W1,
                                               unsigned short* __restrict__ P,
                                               int nwaves) {
    __shared__ unsigned short wlds[512 * 40];   // 40 KB, row stride 80 B
    int tid = threadIdx.x;
    for (int t4 = tid * 4; t4 < 16384; t4 += 1024) {   // 4 consecutive f32 within a row
        f32x4 v = *(const f32x4*)(W1 + t4);
        short4_t o;
#pragma unroll
        for (int e = 0; e < 4; ++e) o[e] = (short)f32_to_bf16(v[e]);
        int rc = t4 >> 5, j = t4 & 31;
        *(short4_t*)&wlds[rc * 40 + j] = o;
    }
    __syncthreads();

    int gw   = (blockIdx.x * 256 + tid) >> 6;
    int lane = tid & 63;
    int col16 = lane & 15, krow = lane >> 4;

    const int NTILES = N_NODES / 16;   // 6250 exact
    for (int tile = gw; tile < NTILES; tile += nwaves) {
        int n0 = tile * 16;
        const float* ap = emb0 + (size_t)(n0 + col16) * 32 + krow * 8;
        f32x4 a0 = *(const f32x4*)ap;
        f32x4 a1 = *(const f32x4*)(ap + 4);
        short8 b;
#pragma unroll
        for (int e = 0; e < 4; ++e) { b[e] = (short)f32_to_bf16(a0[e]); b[e + 4] = (short)f32_to_bf16(a1[e]); }
#pragma unroll
        for (int rcb = 0; rcb < 32; ++rcb) {
            short8 a = *(const short8*)&wlds[(rcb * 16 + col16) * 40 + krow * 8];
            f32x4 c = {0.f, 0.f, 0.f, 0.f};
            c = __builtin_amdgcn_mfma_f32_16x16x32_bf16(a, b, c, 0, 0, 0);
            short4_t o;
#pragma unroll
            for (int reg = 0; reg < 4; ++reg) o[reg] = (short)f32_to_bf16(c[reg]);
            *(short4_t*)(P + (size_t)(n0 + col16) * 512 + rcb * 16 + krow * 4) = o;
        }
    }
}

// ---------------- k_place: node-exact placement (16-padded) + offs/cnt/inv2 ------------
__global__ __launch_bounds__(256) void k_place(const unsigned int* __restrict__ part,
                                               const int* __restrict__ bktbase,
                                               unsigned int* __restrict__ sorted_rd,
                                               int* __restrict__ sorted_src,
                                               int* __restrict__ offs,
                                               int* __restrict__ cnt,
                                               float* __restrict__ inv2) {
    __shared__ int lhist[256 * 16];    // (node-in-bucket, rel) counts
    __shared__ int sd[256];            // scan temp
    __shared__ int lcur[256];          // node cursors
    int b = blockIdx.x, tid = threadIdx.x;
    int n0 = b << 8;
    int braw = bktbase[b];
    int bsize = bktbase[b + 1] - braw;
    int bp = align16i(braw) + b * BKT_PAD;                    // content base (16-aligned)
    int bp_next = align16i(bktbase[b + 1]) + (b + 1) * BKT_PAD;
#pragma unroll
    for (int k = 0; k < 16; ++k) lhist[tid + k * 256] = 0;
    __syncthreads();
    // pass 1: (node,rel) histogram over this bucket's content
    for (int t = bp + tid; t < bp + bsize; t += 256)
        atomicAdd(&lhist[part[t] >> 17], 1);   // (slow<<4)|rel, < 4096
    __syncthreads();
    // per-node counts (raw + padded) + exclusive scan of padded counts
    int ncnt = 0;
#pragma unroll
    for (int r = 0; r < 16; ++r) ncnt += lhist[(tid << 4) | r];
    int ncnt_p = align16i(ncnt);
    sd[tid] = ncnt_p; __syncthreads();
    int x = ncnt_p;
    for (int off = 1; off < 256; off <<= 1) {
        int t = (tid >= off) ? sd[tid - off] : 0;
        __syncthreads();
        x += t; sd[tid] = x;
        __syncthreads();
    }
    int nodeoff = bp + (x - ncnt_p);
    lcur[tid] = nodeoff;
    int node = n0 + tid;
    if (node < N_NODES) { offs[node] = nodeoff; cnt[node] = ncnt; }
    // inv2 emission
    for (int t = tid; t < 4096; t += 256) {
        int nd = n0 + (t >> 4);
        if (nd < N_NODES) {
            int c = lhist[t];
            inv2[((size_t)nd << 4) + (t & 15)] = c ? 1.0f / (float)c : 0.f;
        }
    }
    __syncthreads();
    // pass 2: exact placement of real edges
    for (int t = bp + tid; t < bp + bsize; t += 256) {
        unsigned int v = part[t];
        int j = (int)(v >> 21);
        int p = atomicAdd(&lcur[j], 1);
        sorted_rd[p] = v & 0x1FFFFFu;
        if (b < 4) sorted_src[p] = n0 + j;    // buckets 0..3 = nodes 0..1023
    }
    __syncthreads();
    // pass 3: per-node pad fill (<=15 each) + inter-bucket gap fill
    for (int p = nodeoff + ncnt; p < nodeoff + ncnt_p; ++p) sorted_rd[p] = PAD_FLAG;
    int content_end = bp + sd[255];
    for (int t = content_end + tid; t < bp_next; t += 256) sorted_rd[t] = PAD_FLAG;
}

// ---------------- layer-1 aggregate: wave per node, 32 P-loads in flight ----------------
__global__ __launch_bounds__(256) void k_agg1(const unsigned int* __restrict__ sorted_rd,
                                              const int* __restrict__ offs,
                                              const int* __restrict__ cnt,
                                              const float* __restrict__ inv2,
                                              const unsigned short* __restrict__ P,
                                              float* __restrict__ h1) {
    int node = blockIdx.x * 4 + (threadIdx.x >> 6);   // 25000 x 256 = 100000 waves
    int lane = threadIdx.x & 63;
    int i = lane & 31, h = lane >> 5;
    int start = offs[node];
    int ecp = align16i(cnt[node]);                    // segment 16-aligned + padded
    const float* ivn = inv2 + ((size_t)node << 4);    // 16 floats, one hot line
    float acc = 0.f;
    for (int t0 = start + h * 16; t0 < start + ecp; t0 += 32) {
        uint4 qa = *reinterpret_cast<const uint4*>(sorted_rd + t0);
        uint4 qb = *reinterpret_cast<const uint4*>(sorted_rd + t0 + 4);
        uint4 qc = *reinterpret_cast<const uint4*>(sorted_rd + t0 + 8);
        uint4 qd = *reinterpret_cast<const uint4*>(sorted_rd + t0 + 12);
        unsigned pk[16] = {qa.x, qa.y, qa.z, qa.w, qb.x, qb.y, qb.z, qb.w,
                           qc.x, qc.y, qc.z, qc.w, qd.x, qd.y, qd.z, qd.w};
        float v[16], val[16];
#pragma unroll
        for (int k = 0; k < 16; ++k) {
            unsigned d = pk[k] & 0x1FFFFu, r = (pk[k] >> 17) & 15u;
            v[k]   = bf2f(P[(size_t)d * 512 + r * 32 + i]);   // pad: d=0 hot line
            val[k] = (pk[k] & PAD_FLAG) ? 0.f : ivn[r];
        }
#pragma unroll
        for (int k = 0; k < 16; ++k) acc += val[k] * v[k];
    }
    acc += __shfl_xor(acc, 32, 64);
    if (h == 0) h1[(size_t)node * 32 + i] = fmaxf(acc, 0.f);   // relu fused
}

// ---------------- layer-2 aggregate: agg2[s][r*32+j] += val * h1relu[d][j] ----------------
__global__ void k_agg2(const unsigned int* __restrict__ sorted_rd,
                       const int* __restrict__ sorted_src,
                       const int* __restrict__ bktbase,
                       const float* __restrict__ inv2, const float* __restrict__ h1,
                       float* __restrict__ agg2) {
    int E2 = ((bktbase[4] + 15) & ~15) + 4 * BKT_PAD;   // padded end of buckets 0..3
    long total = (long)E2 * 32;
    long stride = (long)gridDim.x * blockDim.x;
    for (long t = (long)blockIdx.x * blockDim.x + threadIdx.x; t < total; t += stride) {
        int e = (int)(t >> 5), j = (int)(t & 31);
        unsigned int pk = sorted_rd[e];
        if (pk & PAD_FLAG) continue;                   // pad / gap entry
        int r = (int)(pk >> 17), d = (int)(pk & 0x1FFFFu);
        int s = sorted_src[e];
        float val = inv2[((size_t)s << 4) + r];
        atomicAdd(&agg2[(s << 9) + (r << 5) + j], val * h1[(size_t)d * 32 + j]);
    }
}

// ---------------- fused layer-2 transform + classifier (one block per batch row) -------
__global__ __launch_bounds__(64) void k_head(const float* __restrict__ agg2,
                                             const float* __restrict__ W2,
                                             const float* __restrict__ cls_w,
                                             const float* __restrict__ cls_b,
                                             float* __restrict__ out) {
    __shared__ float hr[32];
    int s = blockIdx.x, tid = threadIdx.x;
    if (tid < 32) {
        const float* arow = agg2 + (s << 9);
        float acc = 0.f;
#pragma unroll 4
        for (int r = 0; r < 16; ++r) {
            const float* wrow = W2 + r * 1024 + tid * 32;
            const float* a = arow + r * 32;
#pragma unroll
            for (int j = 0; j < 32; ++j) acc += wrow[j] * a[j];
        }
        hr[tid] = fmaxf(acc, 0.f);     // relu fused
    }
    __syncthreads();
    if (tid < 50) {
        float acc = cls_b[tid];
#pragma unroll
        for (int j = 0; j < 32; ++j) acc += hr[j] * cls_w[tid * 32 + j];
        out[s * 50 + tid] = acc;
    }
}

extern "C" void kernel_launch(void* const* d_in, const int* in_sizes, int n_in,
                              void* d_out, int out_size, void* d_ws, size_t ws_size,
                              hipStream_t stream) {
    const float* emb0  = (const float*)d_in[0];
    const float* W1    = (const float*)d_in[1];
    const float* W2    = (const float*)d_in[2];
    const float* cls_w = (const float*)d_in[3];
    const float* cls_b = (const float*)d_in[4];
    const int*   src   = (const int*)d_in[5];
    const int*   rel   = (const int*)d_in[6];
    const int*   dst   = (const int*)d_in[7];
    float* out = (float*)d_out;

    char* ws = (char*)d_ws;
    size_t off = 0;
    auto alloc = [&](size_t bytes) -> void* {
        void* p = ws + off;
        off = (off + bytes + 255) & ~((size_t)255);
        return p;
    };
    float*          inv2       = (float*)alloc((size_t)N_NODES * 16 * 4);    // 6.4 MB
    int*            offs       = (int*)alloc((size_t)N_NODES * 4);
    int*            cnt        = (int*)alloc((size_t)N_NODES * 4);
    int*            table      = (int*)alloc((size_t)NBLK * NBKT * 4);       // 400 KB
    int*            bktbase    = (int*)alloc((size_t)(NBKT + 1) * 4);
    int*            goff       = (int*)alloc((size_t)NBLK * NBKT * 4);       // 400 KB
    unsigned int*   sorted_rd  = (unsigned int*)alloc((size_t)PADDED_E * 4); // 18.8 MB
    int*            sorted_src = (int*)alloc((size_t)65536 * 4);             // 256 KB (buckets 0..3 only)
    // part and h1 share one buffer: part dies at k_place, h1 is born at k_agg1
    unsigned int*   partX      = (unsigned int*)alloc((size_t)PADDED_E * 4); // 18.8 MB
    unsigned short* P          = (unsigned short*)alloc((size_t)N_NODES * 512 * 2); // 102.4 MB
    float*          agg2       = (float*)alloc((size_t)1024 * 512 * 4);      // 2 MB
    unsigned int*   part       = partX;
    float*          h1         = (float*)partX;

    hipMemsetAsync(agg2, 0, (size_t)1024 * 512 * 4, stream);

    k_histA <<<NBLK, 512, 0, stream>>>(src, table);
    k_bb    <<<1, 512, 0, stream>>>(table, bktbase);
    k_goff  <<<NBKT, NBLK, 0, stream>>>(table, bktbase, goff);
    k_partB <<<NBLK, 512, 0, stream>>>(src, rel, dst, goff, part);
    k_pgemm <<<391, 256, 0, stream>>>(emb0, W1, P, 391 * 4);
    k_place <<<NBKT, 256, 0, stream>>>(part, bktbase, sorted_rd, sorted_src, offs, cnt, inv2);
    k_agg1  <<<25000, 256, 0, stream>>>(sorted_rd, offs, cnt, inv2, P, h1);
    k_agg2  <<<1024, 256, 0, stream>>>(sorted_rd, sorted_src, bktbase, inv2, h1, agg2);
    k_head  <<<1024, 64, 0, stream>>>(agg2, W2, cls_w, cls_b, out);
}